// Round 5
// baseline (88.756 us; speedup 1.0000x reference)
//
#include <hip/hip_runtime.h>

#define NROWS 4096
#define DDIM  256
#define BDIM  16
#define RBLKS 256                  // 16 rows per row-block
#define BSETS 8                    // 2 instances per block
#define GRID1 (RBLKS * BSETS)      // 2048 blocks
#define CNT_OFF 16384              // byte offset of the atomic counter in ws

// Fused kernel. Block (bset, rblk) handles instances b in [2*bset, 2*bset+2)
// for rows [16*rblk, 16*rblk+16). Wave layout: 4 groups of 16 lanes; group g
// owns one row; lane j covers cols {4j+64m : m=0..3} (256 B contiguous per
// group per load -> coalesced). The last block to finish (device-scope atomic
// counter) reduces all 4096 partials in fixed order -> deterministic.
__global__ __launch_bounds__(256) void cos_fused_kernel(
    const float* __restrict__ stat, const float* __restrict__ con,
    const int* __restrict__ lens, float* __restrict__ partial,
    unsigned int* __restrict__ counter, float* __restrict__ out) {
  const int rblk = blockIdx.x & (RBLKS - 1);
  const int bset = blockIdx.x >> 8;          // 0..7
  const int wave = threadIdx.x >> 6;
  const int lane = threadIdx.x & 63;
  const int g    = lane >> 4;                // row-group within wave
  const int j    = lane & 15;                // col-lane within group
  const int n    = rblk * 16 + wave * 4 + g; // this lane's row
  const int b0   = bset * 2;

  __shared__ float sh[4][2];
  __shared__ float shl[BDIM];
  __shared__ unsigned int last;

  #pragma unroll
  for (int bi = 0; bi < 2; ++bi) {
    const int b     = b0 + bi;
    const int len   = lens[b];
    const bool valid = (n < len);

    float dot = 0.0f, ns = 0.0f, nc = 0.0f;
    if (valid) {  // invalid rows: zero memory traffic (uniform per 16-lane group)
      const size_t base = (size_t)b * (NROWS * DDIM) + (size_t)n * DDIM + (j << 2);
      const float* pa = stat + base;
      const float* pc = con + base;
      #pragma unroll
      for (int m = 0; m < 4; ++m) {
        const float4 a = *reinterpret_cast<const float4*>(pa + (m << 6));
        const float4 c = *reinterpret_cast<const float4*>(pc + (m << 6));
        dot = fmaf(a.x, c.x, fmaf(a.y, c.y, fmaf(a.z, c.z, fmaf(a.w, c.w, dot))));
        ns  = fmaf(a.x, a.x, fmaf(a.y, a.y, fmaf(a.z, a.z, fmaf(a.w, a.w, ns))));
        nc  = fmaf(c.x, c.x, fmaf(c.y, c.y, fmaf(c.z, c.z, fmaf(c.w, c.w, nc))));
      }
    }
    // 4-stage butterfly within each 16-lane group
    #pragma unroll
    for (int off = 1; off < 16; off <<= 1) {
      dot += __shfl_xor(dot, off);
      ns  += __shfl_xor(ns,  off);
      nc  += __shfl_xor(nc,  off);
    }
    float cosv = valid ? dot * rsqrtf(ns) * rsqrtf(nc) : 0.0f;  // eps clamp unreachable
    // sum the wave's 4 rows (groups): 2 more stages; all 64 lanes end identical
    cosv += __shfl_xor(cosv, 16);
    cosv += __shfl_xor(cosv, 32);
    if (lane == 0) sh[wave][bi] = cosv;
  }
  __syncthreads();

  // Thread 0 publishes both partials, release-fences, bumps the counter.
  if (threadIdx.x == 0) {
    #pragma unroll
    for (int bi = 0; bi < 2; ++bi) {
      partial[(b0 + bi) * RBLKS + rblk] =
          sh[0][bi] + sh[1][bi] + sh[2][bi] + sh[3][bi];
    }
    __threadfence();                                  // device-scope release
    const unsigned int prev = atomicAdd(counter, 1u); // device-scope by default
    last = (prev == GRID1 - 1) ? 1u : 0u;
  }
  __syncthreads();

  if (last) {
    if (threadIdx.x == 0) __threadfence();            // acquire
    __syncthreads();
    // 4 waves x 4 instances: wave w reduces instances 4w..4w+3 (coalesced).
    #pragma unroll
    for (int bi = 0; bi < 4; ++bi) {
      const int b = wave * 4 + bi;
      float v = 0.0f;
      #pragma unroll
      for (int m = 0; m < 4; ++m) v += partial[b * RBLKS + (m << 6) + lane];
      #pragma unroll
      for (int off = 1; off < 64; off <<= 1) v += __shfl_xor(v, off);
      if (lane == 0) {
        const int len = lens[b];
        shl[b] = (len > 0) ? (1.0f - v / (float)len) : 0.0f;
      }
    }
    __syncthreads();
    if (threadIdx.x == 0) {
      float t = 0.0f;
      #pragma unroll
      for (int i = 0; i < BDIM; ++i) t += shl[i];
      out[0] = t * (1.0f / BDIM);
    }
  }
}

extern "C" void kernel_launch(void* const* d_in, const int* in_sizes, int n_in,
                              void* d_out, int out_size, void* d_ws, size_t ws_size,
                              hipStream_t stream) {
  const float* stat = (const float*)d_in[0];
  const float* con  = (const float*)d_in[1];
  const int*   lens = (const int*)d_in[2];
  float*       out  = (float*)d_out;
  float*       partial = (float*)d_ws;                           // 4096 floats
  unsigned int* counter = (unsigned int*)((char*)d_ws + CNT_OFF);

  // Zero the completion counter (graph-capturable async memset).
  hipMemsetAsync(counter, 0, sizeof(unsigned int), stream);

  dim3 grid(GRID1);
  dim3 blk(256);
  hipLaunchKernelGGL(cos_fused_kernel, grid, blk, 0, stream,
                     stat, con, lens, partial, counter, out);
}

// Round 6
// 20.617 us; speedup vs baseline: 4.3049x; 4.3049x over previous
//
#include <hip/hip_runtime.h>

#define NROWS 4096
#define DDIM  256
#define BDIM  16
#define RBLKS 256           // 16 rows per row-block
#define BSETS 4             // 4 instances per block
#define NB1 (RBLKS * BSETS) // 1024 blocks

// Kernel 1: block = rblk*4 + bset  (rblk fast across CUs!).
// CU c's resident blocks then cover rblk = {c/4, c/4+64, c/4+128, c/4+192} --
// a stratified sample of the row range -> per-CU work balanced for any length
// distribution (the R4 layout put the SAME rblk on all of a CU's blocks,
// giving 2x imbalance).
// Within a wave: 4 groups of 16 lanes; group g owns one row; lane j covers
// cols {4j+64m : m=0..3} (256 B contiguous per group -> coalesced).
__global__ __launch_bounds__(256) void cos_partial_kernel(
    const float* __restrict__ stat, const float* __restrict__ con,
    const int* __restrict__ lens, float* __restrict__ ws) {
  const int rblk = blockIdx.x >> 2;          // 0..255
  const int bset = blockIdx.x & (BSETS - 1); // 0..3
  const int wave = threadIdx.x >> 6;
  const int lane = threadIdx.x & 63;
  const int g    = lane >> 4;                // row-group within wave
  const int j    = lane & 15;                // col-lane within group

  const int n  = rblk * 16 + wave * 4 + g;   // this lane's row
  const int b0 = bset * 4;

  float acc[4];

  #pragma unroll
  for (int bi = 0; bi < 4; ++bi) {
    const int b     = b0 + bi;
    const int len   = lens[b];
    const bool valid = (n < len);

    float dot = 0.0f, ns = 0.0f, nc = 0.0f;
    if (valid) {  // invalid rows: zero memory traffic (uniform per 16-lane group)
      const size_t base = (size_t)b * (NROWS * DDIM) + (size_t)n * DDIM + (j << 2);
      const float* pa = stat + base;
      const float* pc = con + base;
      #pragma unroll
      for (int m = 0; m < 4; ++m) {
        const float4 a = *reinterpret_cast<const float4*>(pa + (m << 6));
        const float4 c = *reinterpret_cast<const float4*>(pc + (m << 6));
        dot = fmaf(a.x, c.x, fmaf(a.y, c.y, fmaf(a.z, c.z, fmaf(a.w, c.w, dot))));
        ns  = fmaf(a.x, a.x, fmaf(a.y, a.y, fmaf(a.z, a.z, fmaf(a.w, a.w, ns))));
        nc  = fmaf(c.x, c.x, fmaf(c.y, c.y, fmaf(c.z, c.z, fmaf(c.w, c.w, nc))));
      }
    }
    // 4-stage butterfly within each 16-lane group
    #pragma unroll
    for (int off = 1; off < 16; off <<= 1) {
      dot += __shfl_xor(dot, off);
      ns  += __shfl_xor(ns,  off);
      nc  += __shfl_xor(nc,  off);
    }
    float cosv = valid ? dot * rsqrtf(ns) * rsqrtf(nc) : 0.0f; // eps clamp unreachable
    // sum the wave's 4 row-groups: 2 more stages (all lanes end identical)
    cosv += __shfl_xor(cosv, 16);
    cosv += __shfl_xor(cosv, 32);
    acc[bi] = cosv;
  }

  __shared__ float sh[4][4];
  if (lane == 0) {
    #pragma unroll
    for (int bi = 0; bi < 4; ++bi) sh[wave][bi] = acc[bi];
  }
  __syncthreads();
  if (threadIdx.x < 4) {
    const int b = b0 + threadIdx.x;
    ws[b * RBLKS + rblk] =
        sh[0][threadIdx.x] + sh[1][threadIdx.x] + sh[2][threadIdx.x] + sh[3][threadIdx.x];
  }
}

// Kernel 2: one block, 256 threads. Wave w reduces instances 4w..4w+3
// (coalesced reads of 256 partials each), thread 0 combines sequentially.
__global__ __launch_bounds__(256) void cos_final_kernel(
    const float* __restrict__ ws, const int* __restrict__ lens,
    float* __restrict__ out, int B) {
  const int wave = threadIdx.x >> 6;
  const int lane = threadIdx.x & 63;

  __shared__ float shl[BDIM];

  #pragma unroll
  for (int bi = 0; bi < 4; ++bi) {
    const int b = wave * 4 + bi;
    float v = 0.0f;
    #pragma unroll
    for (int m = 0; m < RBLKS / 64; ++m) v += ws[b * RBLKS + (m << 6) + lane];
    #pragma unroll
    for (int off = 1; off < 64; off <<= 1) v += __shfl_xor(v, off);
    if (lane == 0) {
      const int len = lens[b];
      shl[b] = (len > 0) ? (1.0f - v / (float)len) : 0.0f;
    }
  }
  __syncthreads();
  if (threadIdx.x == 0) {
    float t = 0.0f;
    #pragma unroll
    for (int i = 0; i < BDIM; ++i) t += shl[i];
    out[0] = t * (1.0f / BDIM);
  }
}

extern "C" void kernel_launch(void* const* d_in, const int* in_sizes, int n_in,
                              void* d_out, int out_size, void* d_ws, size_t ws_size,
                              hipStream_t stream) {
  const float* stat = (const float*)d_in[0];
  const float* con  = (const float*)d_in[1];
  const int*   lens = (const int*)d_in[2];
  float*       out  = (float*)d_out;
  float*       ws   = (float*)d_ws;

  const int B = in_sizes[2];           // 16

  dim3 grid1(NB1);
  dim3 blk1(256);
  hipLaunchKernelGGL(cos_partial_kernel, grid1, blk1, 0, stream, stat, con, lens, ws);

  dim3 grid2(1);
  dim3 blk2(256);
  hipLaunchKernelGGL(cos_final_kernel, grid2, blk2, 0, stream, ws, lens, out, B);
}